// Round 1
// baseline (1264.416 us; speedup 1.0000x reference)
//
#include <hip/hip_runtime.h>

// FusedLoRAQKV on MI355X (gfx950).
// Y_p = X @ (W_p + 2 * B_p @ A_p)^T  for p in {Q,K,V}   (exact refactor of ref)
//
// Pipeline (all on `stream`):
//   1. cvt_x:   X fp32 -> bf16 into d_ws                        (134MB rd, 67MB wr)
//   2. merge_w: W' = bf16(W + 2*B@A) per projection into d_ws   (3x ~100MB traffic)
//   3. gemm:    m97-structure 128x128 tile, BK=64, 4 waves,
//               global_load_lds width=16, mfma_f32_16x16x32_bf16, grid.z = 3
//
// ws layout: Xb [8192][4096] bf16 @ 0 (64 MiB); Wb[3][4096][4096] bf16 @ 64MiB (96 MiB)

typedef unsigned short u16;
typedef __attribute__((ext_vector_type(4))) float  f32x4;
typedef __attribute__((ext_vector_type(8))) __bf16 bf16x8;
typedef __attribute__((ext_vector_type(8))) short  s16x8;

#define MDIM 8192
#define NDIM 4096
#define KDIM 4096
#define BM 128
#define BN 128
#define BK 64

__device__ __forceinline__ u16 f2bf(float f) {
    union { float f; unsigned int u; } v;
    v.f = f;
    unsigned int r = v.u + 0x7FFFu + ((v.u >> 16) & 1u);  // RNE
    return (u16)(r >> 16);
}

// ---------------- Kernel 1: X fp32 -> bf16 ----------------
__global__ void __launch_bounds__(256) cvt_x_kernel(const float* __restrict__ X,
                                                    u16* __restrict__ Xb, int nvec8) {
    int stride = gridDim.x * blockDim.x;
    for (int i = blockIdx.x * blockDim.x + threadIdx.x; i < nvec8; i += stride) {
        f32x4 x0 = ((const f32x4*)X)[2 * i];
        f32x4 x1 = ((const f32x4*)X)[2 * i + 1];
        s16x8 o;
        o[0] = (short)f2bf(x0[0]); o[1] = (short)f2bf(x0[1]);
        o[2] = (short)f2bf(x0[2]); o[3] = (short)f2bf(x0[3]);
        o[4] = (short)f2bf(x1[0]); o[5] = (short)f2bf(x1[1]);
        o[6] = (short)f2bf(x1[2]); o[7] = (short)f2bf(x1[3]);
        ((s16x8*)Xb)[i] = o;
    }
}

// ---------------- Kernel 2: W' = bf16(W + 2*B@A) ----------------
// Block tile: 128 n-rows x 64 h-cols. 256 threads: each does 4 n x 8 h.
// A tile [16][64] staged in LDS; B row (16 fp32) kept in regs (x2 folded in).
__global__ void __launch_bounds__(256) merge_w_kernel(const float* __restrict__ W,
                                                      const float* __restrict__ A,
                                                      const float* __restrict__ Bm,
                                                      u16* __restrict__ Wb) {
    __shared__ float As[16][64];
    const int t  = threadIdx.x;
    const int hb = blockIdx.x * 64;
    const int nb = blockIdx.y * 128;

    {   // stage A[16][hb:hb+64]
        int r = t >> 4, c = (t & 15) * 4;
        *(f32x4*)&As[r][c] = *(const f32x4*)&A[r * 4096 + hb + c];
    }
    __syncthreads();

    const int hl = (t & 7) * 8;           // h offset within tile
    const int n0 = nb + (t >> 3) * 4;     // first of 4 n-rows

    float bv[4][16];
    float s[4][8];
#pragma unroll
    for (int i = 0; i < 4; i++) {
        const float* br = &Bm[(size_t)(n0 + i) * 16];
#pragma unroll
        for (int r = 0; r < 16; r++) bv[i][r] = 2.0f * br[r];
        f32x4 w0 = *(const f32x4*)&W[(size_t)(n0 + i) * 4096 + hb + hl];
        f32x4 w1 = *(const f32x4*)&W[(size_t)(n0 + i) * 4096 + hb + hl + 4];
        s[i][0] = w0[0]; s[i][1] = w0[1]; s[i][2] = w0[2]; s[i][3] = w0[3];
        s[i][4] = w1[0]; s[i][5] = w1[1]; s[i][6] = w1[2]; s[i][7] = w1[3];
    }
#pragma unroll
    for (int r = 0; r < 16; r++) {
        f32x4 a0 = *(const f32x4*)&As[r][hl];
        f32x4 a1 = *(const f32x4*)&As[r][hl + 4];
#pragma unroll
        for (int i = 0; i < 4; i++) {
            s[i][0] += bv[i][r] * a0[0]; s[i][1] += bv[i][r] * a0[1];
            s[i][2] += bv[i][r] * a0[2]; s[i][3] += bv[i][r] * a0[3];
            s[i][4] += bv[i][r] * a1[0]; s[i][5] += bv[i][r] * a1[1];
            s[i][6] += bv[i][r] * a1[2]; s[i][7] += bv[i][r] * a1[3];
        }
    }
#pragma unroll
    for (int i = 0; i < 4; i++) {
        s16x8 o;
#pragma unroll
        for (int j = 0; j < 8; j++) o[j] = (short)f2bf(s[i][j]);
        *(s16x8*)&Wb[(size_t)(n0 + i) * 4096 + hb + hl] = o;
    }
}

// ---------------- Kernel 3: GEMM C = Xb @ Wb^T (m97 structure) ----------------
// 128x128 tile, BK=64, 256 threads (4 waves, 2x2), each wave 64x64 out.
// A/B tiles linear [128][64] bf16 in LDS, staged via global_load_lds width=16.
__global__ void __launch_bounds__(256) gemm_qkv_kernel(const u16* __restrict__ Xb,
                                                       const u16* __restrict__ Wb,
                                                       float* __restrict__ out) {
    __shared__ u16 As[BM * BK];
    __shared__ u16 Bs[BN * BK];

    const int t    = threadIdx.x;
    const int lane = t & 63;
    const int wid  = t >> 6;
    const int wr   = wid >> 1;        // wave row (0..1)
    const int wc   = wid & 1;         // wave col (0..1)
    const int lr   = lane & 15;       // fragment row/col index
    const int lkq  = lane >> 4;       // k-quad (0..3)

    const int mBase = blockIdx.y * BM;
    const int nBase = blockIdx.x * BN;
    const u16* Bp = Wb + (size_t)blockIdx.z * NDIM * KDIM;
    float*     C  = out + (size_t)blockIdx.z * MDIM * NDIM;

    f32x4 acc[4][4] = {};

    for (int kb = 0; kb < KDIM / BK; ++kb) {
        const int k0 = kb * BK;
        // stage A tile: 1024 chunks of 16B, chunk c -> row c>>3, col8 c&7
#pragma unroll
        for (int i = 0; i < 4; i++) {
            int cc  = i * 256 + t;
            int row = cc >> 3, col = (cc & 7) * 8;
            __builtin_amdgcn_global_load_lds(
                (const __attribute__((address_space(1))) void*)(Xb + (size_t)(mBase + row) * KDIM + k0 + col),
                (__attribute__((address_space(3))) void*)(&As[cc * 8]), 16, 0, 0);
        }
#pragma unroll
        for (int i = 0; i < 4; i++) {
            int cc  = i * 256 + t;
            int row = cc >> 3, col = (cc & 7) * 8;
            __builtin_amdgcn_global_load_lds(
                (const __attribute__((address_space(1))) void*)(Bp + (size_t)(nBase + row) * KDIM + k0 + col),
                (__attribute__((address_space(3))) void*)(&Bs[cc * 8]), 16, 0, 0);
        }
        __syncthreads();  // drains vmcnt before barrier (compiler-inserted)

#pragma unroll
        for (int kk = 0; kk < 2; ++kk) {
            bf16x8 a[4], b[4];
#pragma unroll
            for (int mi = 0; mi < 4; mi++)
                a[mi] = *(const bf16x8*)&As[(wr * 64 + mi * 16 + lr) * BK + kk * 32 + lkq * 8];
#pragma unroll
            for (int ni = 0; ni < 4; ni++)
                b[ni] = *(const bf16x8*)&Bs[(wc * 64 + ni * 16 + lr) * BK + kk * 32 + lkq * 8];
#pragma unroll
            for (int mi = 0; mi < 4; mi++)
#pragma unroll
                for (int ni = 0; ni < 4; ni++)
                    acc[mi][ni] = __builtin_amdgcn_mfma_f32_16x16x32_bf16(a[mi], b[ni], acc[mi][ni], 0, 0, 0);
        }
        __syncthreads();
    }

    // epilogue: C/D layout col = lane&15, row = (lane>>4)*4 + reg  [m89-verified]
#pragma unroll
    for (int mi = 0; mi < 4; mi++) {
#pragma unroll
        for (int ni = 0; ni < 4; ni++) {
            const int col  = nBase + wc * 64 + ni * 16 + lr;
            const int row0 = mBase + wr * 64 + mi * 16 + lkq * 4;
            f32x4 v = acc[mi][ni];
#pragma unroll
            for (int j = 0; j < 4; j++)
                C[(size_t)(row0 + j) * NDIM + col] = v[j];
        }
    }
}

// ---------------- host launch ----------------
extern "C" void kernel_launch(void* const* d_in, const int* in_sizes, int n_in,
                              void* d_out, int out_size, void* d_ws, size_t ws_size,
                              hipStream_t stream) {
    const float* X  = (const float*)d_in[0];
    const float* QW = (const float*)d_in[1];
    const float* QA = (const float*)d_in[2];
    const float* QB = (const float*)d_in[3];
    const float* KW = (const float*)d_in[4];
    const float* KA = (const float*)d_in[5];
    const float* KB = (const float*)d_in[6];
    const float* VW = (const float*)d_in[7];
    const float* VA = (const float*)d_in[8];
    const float* VB = (const float*)d_in[9];
    float* out = (float*)d_out;

    u16* Xb = (u16*)d_ws;                                        // 64 MiB
    u16* Wb = (u16*)((char*)d_ws + (size_t)MDIM * KDIM * 2);     // 3 x 32 MiB

    // 1. X -> bf16
    cvt_x_kernel<<<2048, 256, 0, stream>>>(X, Xb, (MDIM * KDIM) / 8);

    // 2. merged weights -> bf16
    dim3 wgrid(4096 / 64, 4096 / 128);
    merge_w_kernel<<<wgrid, 256, 0, stream>>>(QW, QA, QB, Wb + (size_t)0 * NDIM * KDIM);
    merge_w_kernel<<<wgrid, 256, 0, stream>>>(KW, KA, KB, Wb + (size_t)1 * NDIM * KDIM);
    merge_w_kernel<<<wgrid, 256, 0, stream>>>(VW, VA, VB, Wb + (size_t)2 * NDIM * KDIM);

    // 3. three GEMMs (z = projection)
    dim3 ggrid(NDIM / BN, MDIM / BM, 3);
    gemm_qkv_kernel<<<ggrid, 256, 0, stream>>>(Xb, Wb, out);
}

// Round 2
// 802.107 us; speedup vs baseline: 1.5764x; 1.5764x over previous
//
#include <hip/hip_runtime.h>

// FusedLoRAQKV on MI355X (gfx950).
// Y_p = X @ (W_p + 2 * B_p @ A_p)^T  for p in {Q,K,V}
//
// Pipeline:
//   1. cvt_x:   X fp32 -> bf16
//   2. merge_w: W' = bf16(W + 2*B@A)
//   3. gemm8:   256x256 8-phase schedule (m201 template): BK=64, 8 waves,
//               XOR-swizzled LDS, global_load_lds w=16 with pre-swizzled source,
//               counted vmcnt(6), setprio around MFMA clusters, XCD swizzle.

typedef unsigned short u16;
typedef __attribute__((ext_vector_type(4))) float  f32x4;
typedef __attribute__((ext_vector_type(8))) __bf16 bf16x8;
typedef __attribute__((ext_vector_type(8))) short  s16x8;

#define MDIM 8192
#define NDIM 4096
#define KDIM 4096

__device__ __forceinline__ u16 f2bf(float f) {
    union { float f; unsigned int u; } v;
    v.f = f;
    unsigned int r = v.u + 0x7FFFu + ((v.u >> 16) & 1u);  // RNE
    return (u16)(r >> 16);
}

// ---------------- Kernel 1: X fp32 -> bf16 ----------------
__global__ void __launch_bounds__(256) cvt_x_kernel(const float* __restrict__ X,
                                                    u16* __restrict__ Xb, int nvec8) {
    int stride = gridDim.x * blockDim.x;
    for (int i = blockIdx.x * blockDim.x + threadIdx.x; i < nvec8; i += stride) {
        f32x4 x0 = ((const f32x4*)X)[2 * i];
        f32x4 x1 = ((const f32x4*)X)[2 * i + 1];
        s16x8 o;
        o[0] = (short)f2bf(x0[0]); o[1] = (short)f2bf(x0[1]);
        o[2] = (short)f2bf(x0[2]); o[3] = (short)f2bf(x0[3]);
        o[4] = (short)f2bf(x1[0]); o[5] = (short)f2bf(x1[1]);
        o[6] = (short)f2bf(x1[2]); o[7] = (short)f2bf(x1[3]);
        ((s16x8*)Xb)[i] = o;
    }
}

// ---------------- Kernel 2: W' = bf16(W + 2*B@A) ----------------
__global__ void __launch_bounds__(256) merge_w_kernel(const float* __restrict__ W,
                                                      const float* __restrict__ A,
                                                      const float* __restrict__ Bm,
                                                      u16* __restrict__ Wb) {
    __shared__ float As[16][64];
    const int t  = threadIdx.x;
    const int hb = blockIdx.x * 64;
    const int nb = blockIdx.y * 128;

    {   // stage A[16][hb:hb+64]
        int r = t >> 4, c = (t & 15) * 4;
        *(f32x4*)&As[r][c] = *(const f32x4*)&A[r * 4096 + hb + c];
    }
    __syncthreads();

    const int hl = (t & 7) * 8;
    const int n0 = nb + (t >> 3) * 4;

    float bv[4][16];
    float s[4][8];
#pragma unroll
    for (int i = 0; i < 4; i++) {
        const float* br = &Bm[(size_t)(n0 + i) * 16];
#pragma unroll
        for (int r = 0; r < 16; r++) bv[i][r] = 2.0f * br[r];
        f32x4 w0 = *(const f32x4*)&W[(size_t)(n0 + i) * 4096 + hb + hl];
        f32x4 w1 = *(const f32x4*)&W[(size_t)(n0 + i) * 4096 + hb + hl + 4];
        s[i][0] = w0[0]; s[i][1] = w0[1]; s[i][2] = w0[2]; s[i][3] = w0[3];
        s[i][4] = w1[0]; s[i][5] = w1[1]; s[i][6] = w1[2]; s[i][7] = w1[3];
    }
#pragma unroll
    for (int r = 0; r < 16; r++) {
        f32x4 a0 = *(const f32x4*)&As[r][hl];
        f32x4 a1 = *(const f32x4*)&As[r][hl + 4];
#pragma unroll
        for (int i = 0; i < 4; i++) {
            s[i][0] += bv[i][r] * a0[0]; s[i][1] += bv[i][r] * a0[1];
            s[i][2] += bv[i][r] * a0[2]; s[i][3] += bv[i][r] * a0[3];
            s[i][4] += bv[i][r] * a1[0]; s[i][5] += bv[i][r] * a1[1];
            s[i][6] += bv[i][r] * a1[2]; s[i][7] += bv[i][r] * a1[3];
        }
    }
#pragma unroll
    for (int i = 0; i < 4; i++) {
        s16x8 o;
#pragma unroll
        for (int j = 0; j < 8; j++) o[j] = (short)f2bf(s[i][j]);
        *(s16x8*)&Wb[(size_t)(n0 + i) * 4096 + hb + hl] = o;
    }
}

// ---------------- Kernel 3: 256x256 8-phase GEMM ----------------
// C = Xb @ Wb^T.  8 waves (2M x 4N), per-wave 128x64 out, acc[8][4].
// LDS 128 KiB: A[2][256][64] + B[2][256][64] bf16, XOR-swizzled (col16B ^= row&7).
// Staging: global_load_lds w=16, linear LDS dst, pre-swizzled global src (rule 21).
// Schedule: 8 phases / 2 K-tiles, 1 half-tile staged per phase, vmcnt(6) at P4/P8.

#define BM 256
#define BN 256
#define BK 64
#define NKT (KDIM / BK)   // 64

#define BAR() __builtin_amdgcn_s_barrier()
#define WAIT_LGKM0() asm volatile("s_waitcnt lgkmcnt(0)" ::: "memory")
#define WAIT_VM(n) asm volatile("s_waitcnt vmcnt(" #n ")" ::: "memory")
#define PRIO(p) __builtin_amdgcn_s_setprio(p)

__global__ void __launch_bounds__(512, 2) gemm8_kernel(const u16* __restrict__ Xb,
                                                       const u16* __restrict__ Wb,
                                                       float* __restrict__ out) {
    extern __shared__ char lds[];

    const int t    = threadIdx.x;
    const int lane = t & 63;
    const int w    = t >> 6;      // wave 0..7
    const int wr   = w >> 2;      // M wave 0..1
    const int wn   = w & 3;       // N wave 0..3
    const int lr   = lane & 15;
    const int lkq  = lane >> 4;
    const int lr7  = lr & 7;

    // XCD-bijective remap: 1536 blocks, 8 XCDs x 192
    int wg = blockIdx.x;
    wg = (wg & 7) * 192 + (wg >> 3);
    const int z  = wg >> 9;                 // /512 (blocks per projection)
    const int r_ = wg & 511;
    const int nT = r_ & 15;                 // 16 n-tiles
    const int mT = r_ >> 4;                 // 32 m-tiles
    const int mBase = mT * BM;
    const int nBase = nT * BN;

    const u16* Wp = Wb + (size_t)z * NDIM * KDIM;
    const char* gA = (const char*)Xb + (size_t)mBase * (KDIM * 2);
    const char* gB = (const char*)Wp + (size_t)nBase * (KDIM * 2);

    char* ldsA0 = lds;
    char* ldsA1 = lds + 32768;
    char* ldsB0 = lds + 65536;
    char* ldsB1 = lds + 98304;

    // staging geometry: instr j in {0,1}: blk = w*2+j (16 x 1024B blocks per half)
    // lane covers LDS (row = blk*8 + lane>>3, colbyte = (lane&7)*16); global src
    // col pre-swizzled: colswz = 16*((lane&7) ^ (lane>>3))   [row&7 == lane>>3]
    const int blkrow = lane >> 3;
    const int colswz = ((lane & 7) ^ blkrow) << 4;
    const size_t stg0 = (size_t)(((w << 1) | 0) * 8 + blkrow) * (KDIM * 2) + colswz;
    const size_t stg1 = (size_t)(((w << 1) | 1) * 8 + blkrow) * (KDIM * 2) + colswz;
    const int ldsStg0 = (((w << 1) | 0) << 10) + lane * 16;
    const int ldsStg1 = (((w << 1) | 1) << 10) + lane * 16;

#define STAGE(ldsTile, gtile, h, kt)                                              \
  { __builtin_amdgcn_global_load_lds(                                             \
        (const __attribute__((address_space(1))) void*)((gtile) + stg0 +          \
            (size_t)(h) * (128 * KDIM * 2) + (size_t)(kt) * 128),                 \
        (__attribute__((address_space(3))) void*)((ldsTile) + (h) * 16384 + ldsStg0), \
        16, 0, 0);                                                                \
    __builtin_amdgcn_global_load_lds(                                             \
        (const __attribute__((address_space(1))) void*)((gtile) + stg1 +          \
            (size_t)(h) * (128 * KDIM * 2) + (size_t)(kt) * 128),                 \
        (__attribute__((address_space(3))) void*)((ldsTile) + (h) * 16384 + ldsStg1), \
        16, 0, 0); }

    // ds_read addressing: row*128 + ((kk<<6)|(lkq<<4)) ^ ((row&7)<<4); row&7 == lr7
    const int csA = (lkq << 4) ^ (lr7 << 4);
    const int rA0 = (wr * 128 + lr) * 128;
    const int rB0 = (wn * 64 + lr) * 128;
#define RD_A(tile, mi, kk) (*(const bf16x8*)((tile) + rA0 + (mi) * 2048 + (((kk) << 6) ^ csA)))
#define RD_B(tile, ni, kk) (*(const bf16x8*)((tile) + rB0 + (ni) * 2048 + (((kk) << 6) ^ csA)))

    f32x4 acc[8][4] = {};
    bf16x8 aR1[4][2], aR2[4][2], bR[4][2];

#define MFMA_Q(AF, mbase, nbase)                                                   \
    PRIO(1);                                                                       \
    _Pragma("unroll") for (int mi = 0; mi < 4; ++mi)                               \
    _Pragma("unroll") for (int ni = 0; ni < 2; ++ni)                               \
    _Pragma("unroll") for (int kk = 0; kk < 2; ++kk)                               \
      acc[(mbase) + mi][(nbase) + ni] = __builtin_amdgcn_mfma_f32_16x16x32_bf16(   \
          AF[mi][kk], bR[(nbase) + ni][kk], acc[(mbase) + mi][(nbase) + ni], 0, 0, 0); \
    PRIO(0);

// P1: read A mi0-3 (8) + B ni0-3 (8); MFMA m0-3 x n0-1
#define PH1(pA, pB, STG)                                                           \
  { _Pragma("unroll") for (int mi = 0; mi < 4; ++mi) {                             \
      aR1[mi][0] = RD_A(pA, mi, 0); aR1[mi][1] = RD_A(pA, mi, 1); }                \
    _Pragma("unroll") for (int ni = 0; ni < 4; ++ni) {                             \
      bR[ni][0] = RD_B(pB, ni, 0); bR[ni][1] = RD_B(pB, ni, 1); }                  \
    STG; BAR(); WAIT_LGKM0(); MFMA_Q(aR1, 0, 0) BAR(); }

// P2: read A mi4-5 (4); MFMA m0-3 x n2-3
#define PH2(pA, STG)                                                               \
  { aR2[0][0] = RD_A(pA, 4, 0); aR2[0][1] = RD_A(pA, 4, 1);                        \
    aR2[1][0] = RD_A(pA, 5, 0); aR2[1][1] = RD_A(pA, 5, 1);                        \
    STG; BAR(); WAIT_LGKM0(); MFMA_Q(aR1, 0, 2) BAR(); }

// P3: read A mi6-7 (4); MFMA m4-7 x n0-1
#define PH3(pA, STG)                                                               \
  { aR2[2][0] = RD_A(pA, 6, 0); aR2[2][1] = RD_A(pA, 6, 1);                        \
    aR2[3][0] = RD_A(pA, 7, 0); aR2[3][1] = RD_A(pA, 7, 1);                        \
    STG; BAR(); WAIT_LGKM0(); MFMA_Q(aR2, 4, 0) BAR(); }

// P4: no reads; MFMA m4-7 x n2-3; vmcnt before BAR1
#define PH4(STG, VMW)                                                              \
  { STG; VMW; BAR(); WAIT_LGKM0(); MFMA_Q(aR2, 4, 2) BAR(); }

    // ---- prologue: t0 all 4 halves -> buf0; t1 Bh0,Bh1,Ah0 -> buf1 ----
    STAGE(ldsA0, gA, 0, 0); STAGE(ldsA0, gA, 1, 0);
    STAGE(ldsB0, gB, 0, 0); STAGE(ldsB0, gB, 1, 0);
    STAGE(ldsB1, gB, 0, 1); STAGE(ldsB1, gB, 1, 1);
    STAGE(ldsA1, gA, 0, 1);
    WAIT_VM(6);
    BAR();

    // ---- main loop: 31 iterations, t = 0..60 even ----
    for (int i = 0; i < 31; ++i) {
        const int tt = 2 * i;
        PH1(ldsA0, ldsB0, STAGE(ldsA1, gA, 1, tt + 1));   // (t+1).Ah1 -> buf1
        PH2(ldsA0,        STAGE(ldsB0, gB, 0, tt + 2));   // (t+2).Bh0 -> buf0
        PH3(ldsA0,        STAGE(ldsB0, gB, 1, tt + 2));   // (t+2).Bh1 -> buf0
        PH4(              STAGE(ldsA0, gA, 0, tt + 2), WAIT_VM(6));  // (t+2).Ah0
        PH1(ldsA1, ldsB1, STAGE(ldsA0, gA, 1, tt + 2));   // (t+2).Ah1 -> buf0
        PH2(ldsA1,        STAGE(ldsB1, gB, 0, tt + 3));   // (t+3).Bh0 -> buf1
        PH3(ldsA1,        STAGE(ldsB1, gB, 1, tt + 3));   // (t+3).Bh1 -> buf1
        PH4(              STAGE(ldsA1, gA, 0, tt + 3), WAIT_VM(6));  // (t+3).Ah0
    }

    // ---- peeled last iteration: t = 62,63 ----
    PH1(ldsA0, ldsB0, STAGE(ldsA1, gA, 1, 63));           // 63.Ah1 (last stage)
    PH2(ldsA0, );
    PH3(ldsA0, );
    PH4(, WAIT_VM(0));
    PH1(ldsA1, ldsB1, );
    PH2(ldsA1, );
    PH3(ldsA1, );
    PH4(, );

    // ---- epilogue: C/D layout col = lane&15, row = (lane>>4)*4 + reg ----
    float* C = out + (size_t)z * MDIM * NDIM;
#pragma unroll
    for (int mi = 0; mi < 8; ++mi) {
#pragma unroll
        for (int ni = 0; ni < 4; ++ni) {
            const int col  = nBase + wn * 64 + ni * 16 + lr;
            const int row0 = mBase + wr * 128 + mi * 16 + lkq * 4;
            f32x4 v = acc[mi][ni];
#pragma unroll
            for (int j = 0; j < 4; ++j)
                C[(size_t)(row0 + j) * NDIM + col] = v[j];
        }
    }
}

// ---------------- host launch ----------------
extern "C" void kernel_launch(void* const* d_in, const int* in_sizes, int n_in,
                              void* d_out, int out_size, void* d_ws, size_t ws_size,
                              hipStream_t stream) {
    const float* X  = (const float*)d_in[0];
    const float* QW = (const float*)d_in[1];
    const float* QA = (const float*)d_in[2];
    const float* QB = (const float*)d_in[3];
    const float* KW = (const float*)d_in[4];
    const float* KA = (const float*)d_in[5];
    const float* KB = (const float*)d_in[6];
    const float* VW = (const float*)d_in[7];
    const float* VA = (const float*)d_in[8];
    const float* VB = (const float*)d_in[9];
    float* out = (float*)d_out;

    u16* Xb = (u16*)d_ws;                                        // 64 MiB
    u16* Wb = (u16*)((char*)d_ws + (size_t)MDIM * KDIM * 2);     // 3 x 32 MiB

    // allow 128 KiB dynamic LDS (no-op if already allowed)
    static bool attr_done = false;
    if (!attr_done) {
        (void)hipFuncSetAttribute((const void*)gemm8_kernel,
                                  hipFuncAttributeMaxDynamicSharedMemorySize, 131072);
        attr_done = true;
    }

    cvt_x_kernel<<<2048, 256, 0, stream>>>(X, Xb, (MDIM * KDIM) / 8);

    dim3 wgrid(4096 / 64, 4096 / 128);
    merge_w_kernel<<<wgrid, 256, 0, stream>>>(QW, QA, QB, Wb + (size_t)0 * NDIM * KDIM);
    merge_w_kernel<<<wgrid, 256, 0, stream>>>(KW, KA, KB, Wb + (size_t)1 * NDIM * KDIM);
    merge_w_kernel<<<wgrid, 256, 0, stream>>>(VW, VA, VB, Wb + (size_t)2 * NDIM * KDIM);

    gemm8_kernel<<<dim3(16 * 32 * 3), dim3(512), 131072, stream>>>(Xb, Wb, out);
}